// Round 2
// baseline (809.517 us; speedup 1.0000x reference)
//
#include <hip/hip_runtime.h>
#include <hip/hip_bf16.h>
#include <math.h>
#include <float.h>

#ifndef M_PI
#define M_PI 3.14159265358979323846
#endif

// Problem constants
#define NBANDS 160      // B*NB = 32*5
#define RR 96           // rows per band
#define TT 2048         // time samples
#define NTRIL 4560      // 96*95/2
#define SORTN 8192      // padded sort size
#define A_ELEMS ((size_t)NBANDS * RR * RR)

// ---------- block reductions (256 threads) ----------
__device__ inline double blockReduceSum(double v, double* sred) {
    for (int off = 32; off > 0; off >>= 1) v += __shfl_down(v, off, 64);
    int lane = threadIdx.x & 63, wid = threadIdx.x >> 6;
    if (lane == 0) sred[wid] = v;
    __syncthreads();
    int nw = (blockDim.x + 63) >> 6;
    if (threadIdx.x == 0) {
        double r = sred[0];
        for (int i = 1; i < nw; i++) r += sred[i];
        sred[0] = r;
    }
    __syncthreads();
    double r = sred[0];
    __syncthreads();
    return r;
}

__device__ inline double blockReduceMax(double v, double* sred) {
    for (int off = 32; off > 0; off >>= 1) v = fmax(v, __shfl_down(v, off, 64));
    int lane = threadIdx.x & 63, wid = threadIdx.x >> 6;
    if (lane == 0) sred[wid] = v;
    __syncthreads();
    int nw = (blockDim.x + 63) >> 6;
    if (threadIdx.x == 0) {
        double r = sred[0];
        for (int i = 1; i < nw; i++) r = fmax(r, sred[i]);
        sred[0] = r;
    }
    __syncthreads();
    double r = sred[0];
    __syncthreads();
    return r;
}

// ---------- K0: twiddle table  tw[k] = exp(-2*pi*i*k/2048), k<1024 ----------
__global__ void twiddle_kernel(double* tw) {
    int k = blockIdx.x * blockDim.x + threadIdx.x;
    if (k < 1024) {
        double ang = -2.0 * M_PI * (double)k / 2048.0;
        tw[2 * k]     = cos(ang);
        tw[2 * k + 1] = sin(ang);
    }
}

// ---------- K1: per-row stats + FFT power-spectrum entropy ----------
// Two rows per block packed into one complex FFT.
// rowstats layout per row g: [mean, norm_guarded, std, energy, maxamp, ent]
__global__ __launch_bounds__(256) void rowstat_fft_kernel(
    const float* __restrict__ wc, const double* __restrict__ tw,
    double* __restrict__ rowstats)
{
    __shared__ double re[TT];
    __shared__ double im[TT];
    __shared__ double sred[8];

    int t = threadIdx.x;
    int g0 = blockIdx.x * 2;          // global row index (even); 96 even -> pair in same band
    int g1 = g0 + 1;

    // row g -> band = g/96, r = g%96 ; band = b*5+nb
    // offset = ((b*96 + r)*5 + nb)*2048
    int band = g0 / RR, r0 = g0 % RR;
    int b = band / 5, nb = band % 5;
    size_t base0 = ((size_t)(b * RR + r0) * 5 + nb) * TT;
    size_t base1 = base0 + (size_t)5 * TT;   // next row, same band/nb

    double s0 = 0, s1 = 0, q0 = 0, q1 = 0, m0 = 0, m1 = 0;
    for (int c = 0; c < 8; c++) {
        int i = t + c * 256;
        double a = (double)wc[base0 + i];
        double bb = (double)wc[base1 + i];
        re[i] = a; im[i] = bb;
        s0 += a; s1 += bb;
        q0 += a * a; q1 += bb * bb;
        m0 = fmax(m0, fabs(a)); m1 = fmax(m1, fabs(bb));
    }
    __syncthreads();

    double SUM0 = blockReduceSum(s0, sred);
    double SUM1 = blockReduceSum(s1, sred);
    double SQ0  = blockReduceSum(q0, sred);
    double SQ1  = blockReduceSum(q1, sred);
    double MX0  = blockReduceMax(m0, sred);
    double MX1  = blockReduceMax(m1, sred);

    // bit-reverse permutation (11 bits)
    for (int c = 0; c < 8; c++) {
        int i = t + c * 256;
        int j = (int)(__brev((unsigned)i) >> 21);
        if (j > i) {
            double tr = re[i]; re[i] = re[j]; re[j] = tr;
            double ti = im[i]; im[i] = im[j]; im[j] = ti;
        }
    }
    __syncthreads();

    // radix-2 DIT stages
    for (int s = 1; s <= 11; s++) {
        int half = 1 << (s - 1);
        int m = 1 << s;
        for (int c = 0; c < 4; c++) {
            int bfly = t + c * 256;        // 0..1023
            int grp = bfly >> (s - 1);
            int pos = bfly & (half - 1);
            int i = grp * m + pos;
            int j = i + half;
            int k = pos << (11 - s);
            double wr = tw[2 * k], wi = tw[2 * k + 1];
            double xr = re[j], xi = im[j];
            double tr = wr * xr - wi * xi;
            double ti = wr * xi + wi * xr;
            double ur = re[i], ui = im[i];
            re[j] = ur - tr; im[j] = ui - ti;
            re[i] = ur + tr; im[i] = ui + ti;
        }
        __syncthreads();
    }

    // unpack two real spectra from packed complex FFT; power spectrum k=0..1023
    double psa[4], psb[4];
    for (int c = 0; c < 4; c++) {
        int k = t + c * 256;               // 0..1023
        int j = (TT - k) & (TT - 1);
        double ar = re[k], ai = im[k];
        double br = re[j], bi = im[j];
        double x1r = 0.5 * (ar + br), x1i = 0.5 * (ai - bi);
        double x2r = 0.5 * (ai + bi), x2i = 0.5 * (br - ar);
        psa[c] = x1r * x1r + x1i * x1i;
        psb[c] = x2r * x2r + x2i * x2i;
    }
    __syncthreads();
    for (int c = 0; c < 4; c++) {
        int k = t + c * 256;
        re[k] = psa[c];
        im[k] = psb[c];
    }
    __syncthreads();

    double ls0 = 0, ls1 = 0;
    for (int c = 0; c < 4; c++) {
        int k = t + c * 256;
        ls0 += re[k]; ls1 += im[k];
    }
    double S0 = blockReduceSum(ls0, sred);
    double S1 = blockReduceSum(ls1, sred);
    if (S0 == 0.0) S0 = 1.0;
    if (S1 == 0.0) S1 = 1.0;

    double e0 = 0, e1 = 0;
    for (int c = 0; c < 4; c++) {
        int k = t + c * 256;
        double p0 = re[k] / S0, p1 = im[k] / S1;
        e0 += p0 * log(p0 + 1e-10);
        e1 += p1 * log(p1 + 1e-10);
    }
    double E0 = blockReduceSum(e0, sred);
    double E1 = blockReduceSum(e1, sred);

    if (t == 0) {
        double mean0 = SUM0 / (double)TT;
        double mean1 = SUM1 / (double)TT;
        double nsq0 = SQ0 - (double)TT * mean0 * mean0; if (nsq0 < 0) nsq0 = 0;
        double nsq1 = SQ1 - (double)TT * mean1 * mean1; if (nsq1 < 0) nsq1 = 0;
        double* o0 = rowstats + (size_t)g0 * 6;
        double* o1 = rowstats + (size_t)g1 * 6;
        double n0 = sqrt(nsq0), n1 = sqrt(nsq1);
        o0[0] = mean0; o0[1] = (n0 == 0.0 ? 1.0 : n0); o0[2] = sqrt(nsq0 / 2047.0);
        o0[3] = SQ0;   o0[4] = MX0;                    o0[5] = -E0;
        o1[0] = mean1; o1[1] = (n1 == 0.0 ? 1.0 : n1); o1[2] = sqrt(nsq1 / 2047.0);
        o1[3] = SQ1;   o1[4] = MX1;                    o1[5] = -E1;
    }
}

// ---------- K2: Gram -> correlation matrix C (fp64 accum, fp32 out into A_out) ----------
// grid = NBANDS * 3 ; block computes rows [tile*32, tile*32+32) x all 96 cols
__global__ __launch_bounds__(256) void gram_kernel(
    const float* __restrict__ wc, const double* __restrict__ rowstats,
    float* __restrict__ C)
{
    __shared__ float Bs[RR][132];
    int band = blockIdx.x / 3, tile = blockIdx.x % 3;
    int b = band / 5, nb = band % 5;
    size_t bandbase = ((size_t)b * RR * 5 + nb) * TT;   // + r*5*2048

    int t = threadIdx.x;
    int ty = t >> 3;           // 0..31 -> row in tile
    int tx = t & 7;            // 0..7
    int row = tile * 32 + ty;  // 0..95

    double acc[12];
#pragma unroll
    for (int cc = 0; cc < 12; cc++) acc[cc] = 0.0;

    for (int k0 = 0; k0 < TT; k0 += 128) {
        for (int idx = t; idx < RR * 32; idx += 256) {
            int r = idx >> 5, c4 = idx & 31;
            float4 v = *(const float4*)(wc + bandbase + (size_t)r * (5 * TT) + k0 + c4 * 4);
            Bs[r][c4 * 4 + 0] = v.x; Bs[r][c4 * 4 + 1] = v.y;
            Bs[r][c4 * 4 + 2] = v.z; Bs[r][c4 * 4 + 3] = v.w;
        }
        __syncthreads();
        for (int kk = 0; kk < 128; kk++) {
            double a = (double)Bs[row][kk];
#pragma unroll
            for (int cc = 0; cc < 12; cc++) {
                double bb = (double)Bs[tx + cc * 8][kk];
                acc[cc] = fma(a, bb, acc[cc]);
            }
        }
        __syncthreads();
    }

    const double* rsi = rowstats + (size_t)(band * RR + row) * 6;
    double mu_i = rsi[0], nm_i = rsi[1];
#pragma unroll
    for (int cc = 0; cc < 12; cc++) {
        int col = tx + cc * 8;
        const double* rsj = rowstats + (size_t)(band * RR + col) * 6;
        double mu_j = rsj[0], nm_j = rsj[1];
        double c = (acc[cc] - (double)TT * mu_i * mu_j) / (nm_i * nm_j);
        if (row == col) c = 0.0;
        C[(size_t)band * (RR * RR) + (size_t)row * RR + col] = (float)c;
    }
}

// ---------- K3: per-band 0.8-quantile of |C[tril]| via bitonic sort (fp32) ----------
__global__ __launch_bounds__(1024) void quantile_kernel(
    const float* __restrict__ C, double* __restrict__ thr)
{
    __shared__ float v[SORTN];
    int band = blockIdx.x, t = threadIdx.x;
    const float* Cb = C + (size_t)band * (RR * RR);

    for (int idx = t; idx < SORTN; idx += 1024) {
        float val = FLT_MAX;
        if (idx < NTRIL) {
            int i = (int)((1.0 + sqrt(8.0 * (double)idx + 1.0)) * 0.5);
            while (i * (i - 1) / 2 > idx) i--;
            while ((i + 1) * i / 2 <= idx) i++;
            int j = idx - i * (i - 1) / 2;
            val = fabsf(Cb[(size_t)i * RR + j]);
        }
        v[idx] = val;
    }
    __syncthreads();

    for (int k = 2; k <= SORTN; k <<= 1) {
        for (int j = k >> 1; j > 0; j >>= 1) {
            for (int c = 0; c < SORTN / 1024; c++) {
                int idx = t + c * 1024;
                int l = idx ^ j;
                if (l > idx) {
                    bool asc = (idx & k) == 0;
                    float a = v[idx], bb = v[l];
                    if (asc ? (a > bb) : (a < bb)) { v[idx] = bb; v[l] = a; }
                }
            }
            __syncthreads();
        }
    }

    if (t == 0) {
        double pos = 0.8 * (double)(NTRIL - 1);   // 3647.2
        int lo = (int)pos;
        double frac = pos - (double)lo;
        thr[band] = (double)v[lo] + frac * ((double)v[lo + 1] - (double)v[lo]);
    }
}

// ---------- K4: graph props + node features + MLP; masks A in place, writes F ----------
__global__ __launch_bounds__(256) void graph_feat_kernel(
    const double* __restrict__ thrA,
    const double* __restrict__ rowstats, const int* __restrict__ community,
    const float* __restrict__ W1, const float* __restrict__ b1,
    const float* __restrict__ W2, const float* __restrict__ b2,
    float* __restrict__ A_out, float* __restrict__ F_out)
{
    __shared__ unsigned char Bm[RR][RR];
    __shared__ unsigned long long msk[RR][2];
    __shared__ int deg[RR];
    __shared__ double sred[8];
    __shared__ double feat[11];
    __shared__ double h[32];

    int band = blockIdx.x, t = threadIdx.x;
    double thr = thrA[band];
    float* Ab = A_out + (size_t)band * (RR * RR);

    for (int idx = t; idx < RR * RR; idx += 256) {
        float c = Ab[idx];
        bool keep = ((double)fabsf(c) >= thr);
        Bm[idx / RR][idx % RR] = (keep && c != 0.0f) ? 1 : 0;
        Ab[idx] = keep ? c : 0.0f;
    }
    __syncthreads();

    if (t < RR) {
        unsigned long long m0 = 0, m1 = 0; int d = 0;
        for (int j = 0; j < RR; j++) {
            if (Bm[t][j]) { d++; if (j < 64) m0 |= (1ull << j); else m1 |= (1ull << (j - 64)); }
        }
        msk[t][0] = m0; msk[t][1] = m1; deg[t] = d;
    }
    __syncthreads();

    double triord = 0, ein = 0, expin = 0;
    for (int idx = t; idx < RR * RR; idx += 256) {
        int i = idx / RR, j = idx % RR;
        if (Bm[i][j])
            triord += (double)(__popcll(msk[i][0] & msk[j][0]) +
                               __popcll(msk[i][1] & msk[j][1]));
        if (i != j && community[i] == community[j]) {
            ein += (double)Bm[i][j];
            expin += (double)deg[i] * (double)deg[j];
        }
    }
    double TRI   = blockReduceSum(triord, sred);
    double EIN   = blockReduceSum(ein, sred);
    double EXPIN = blockReduceSum(expin, sred);
    double dv = (t < RR) ? (double)deg[t] : 0.0;
    double DEGS = blockReduceSum(dv, sred);
    double POSS2 = blockReduceSum((t < RR) ? dv * (dv - 1.0) : 0.0, sred);

    const double* rs = rowstats + (size_t)band * RR * 6;
    double N0 = blockReduceSum((t < RR) ? rs[t * 6 + 0] : 0.0, sred); // mean
    double N1 = blockReduceSum((t < RR) ? rs[t * 6 + 2] : 0.0, sred); // std
    double N2 = blockReduceSum((t < RR) ? rs[t * 6 + 3] : 0.0, sred); // energy
    double N3 = blockReduceSum((t < RR) ? rs[t * 6 + 4] : 0.0, sred); // maxamp
    double N4 = blockReduceSum((t < RR) ? rs[t * 6 + 5] : 0.0, sred); // ent

    if (t == 0) {
        double ne = 0.5 * DEGS;
        feat[0] = N0 / (double)RR;
        feat[1] = N1 / (double)RR;
        feat[2] = N2 / (double)RR;
        feat[3] = N3 / (double)RR;
        feat[4] = N4 / (double)RR;
        feat[5] = ne;
        feat[6] = ne / (double)NTRIL;
        feat[7] = DEGS / (double)RR;
        double tri = TRI / 6.0, poss = POSS2 * 0.5;
        feat[8] = (poss > 0.0) ? tri / poss : 0.0;
        feat[9] = ((double)RR + DEGS) / ((double)RR * (double)(RR - 1));
        double m2 = DEGS;
        feat[10] = (m2 > 0.0) ? (EIN - EXPIN / m2) / m2 : 0.0;
    }
    __syncthreads();

    if (t < 32) {
        double a = (double)b1[t];
        for (int k = 0; k < 11; k++) a += (double)W1[t * 11 + k] * feat[k];
        h[t] = (a > 0.0) ? a : 0.0;
    }
    __syncthreads();
    if (t < 64) {
        double a = (double)b2[t];
        for (int j = 0; j < 32; j++) a += (double)W2[t * 32 + j] * h[j];
        F_out[(size_t)band * 64 + t] = (float)a;
    }
}

extern "C" void kernel_launch(void* const* d_in, const int* in_sizes, int n_in,
                              void* d_out, int out_size, void* d_ws, size_t ws_size,
                              hipStream_t stream) {
    const float* wc        = (const float*)d_in[0];
    // d_in[1] frequency_bands: unused by the reference math
    const int*   community = (const int*)d_in[2];
    const float* W1        = (const float*)d_in[3];
    const float* b1        = (const float*)d_in[4];
    const float* W2        = (const float*)d_in[5];
    const float* b2        = (const float*)d_in[6];

    float* A_out = (float*)d_out;          // C staged here fp32, then masked in place
    float* F_out = A_out + A_ELEMS;

    // workspace: tw 16384 B | rowstats 15360*6*8 = 737280 B | thr 160*8 B  => ~755 KB
    char* ws = (char*)d_ws;
    double* tw       = (double*)ws;
    double* rowstats = (double*)(ws + 16384);
    double* thr      = (double*)(ws + 16384 + 737280);

    hipLaunchKernelGGL(twiddle_kernel, dim3(4), dim3(256), 0, stream, tw);
    hipLaunchKernelGGL(rowstat_fft_kernel, dim3(NBANDS * RR / 2), dim3(256), 0, stream,
                       wc, tw, rowstats);
    hipLaunchKernelGGL(gram_kernel, dim3(NBANDS * 3), dim3(256), 0, stream,
                       wc, rowstats, A_out);
    hipLaunchKernelGGL(quantile_kernel, dim3(NBANDS), dim3(1024), 0, stream, A_out, thr);
    hipLaunchKernelGGL(graph_feat_kernel, dim3(NBANDS), dim3(256), 0, stream,
                       thr, rowstats, community, W1, b1, W2, b2, A_out, F_out);
}

// Round 3
// 534.511 us; speedup vs baseline: 1.5145x; 1.5145x over previous
//
#include <hip/hip_runtime.h>
#include <hip/hip_bf16.h>
#include <math.h>
#include <float.h>

#ifndef M_PI
#define M_PI 3.14159265358979323846
#endif

// Problem constants
#define NBANDS 160      // B*NB = 32*5
#define RR 96           // rows per band
#define TT 2048         // time samples
#define NTRIL 4560      // 96*95/2
#define A_ELEMS ((size_t)NBANDS * RR * RR)
#define NBIN 16384
#define MAXCAND 512

// ---------- block reductions (256 threads) ----------
__device__ inline double blockReduceSum(double v, double* sred) {
    for (int off = 32; off > 0; off >>= 1) v += __shfl_down(v, off, 64);
    int lane = threadIdx.x & 63, wid = threadIdx.x >> 6;
    if (lane == 0) sred[wid] = v;
    __syncthreads();
    int nw = (blockDim.x + 63) >> 6;
    if (threadIdx.x == 0) {
        double r = sred[0];
        for (int i = 1; i < nw; i++) r += sred[i];
        sred[0] = r;
    }
    __syncthreads();
    double r = sred[0];
    __syncthreads();
    return r;
}

__device__ inline double blockReduceMax(double v, double* sred) {
    for (int off = 32; off > 0; off >>= 1) v = fmax(v, __shfl_down(v, off, 64));
    int lane = threadIdx.x & 63, wid = threadIdx.x >> 6;
    if (lane == 0) sred[wid] = v;
    __syncthreads();
    int nw = (blockDim.x + 63) >> 6;
    if (threadIdx.x == 0) {
        double r = sred[0];
        for (int i = 1; i < nw; i++) r = fmax(r, sred[i]);
        sred[0] = r;
    }
    __syncthreads();
    double r = sred[0];
    __syncthreads();
    return r;
}

// ---------- K0: twiddle table  tw[k] = exp(-2*pi*i*k/2048), k<1024 (fp32) ----------
__global__ void twiddle_kernel(float* tw) {
    int k = blockIdx.x * blockDim.x + threadIdx.x;
    if (k < 1024) {
        double ang = -2.0 * M_PI * (double)k / 2048.0;
        tw[2 * k]     = (float)cos(ang);
        tw[2 * k + 1] = (float)sin(ang);
    }
}

// ---------- K1: per-row stats + fp32 FFT power-spectrum entropy ----------
// Two rows per block packed into one complex FFT.
// rowstats layout per row g: [mean, norm_guarded, std, energy, maxamp, ent]
__global__ __launch_bounds__(256) void rowstat_fft_kernel(
    const float* __restrict__ wc, const float* __restrict__ tw,
    double* __restrict__ rowstats)
{
    __shared__ float re[TT];
    __shared__ float im[TT];
    __shared__ double sred[8];

    int t = threadIdx.x;
    int g0 = blockIdx.x * 2;          // global row index (even); 96 even -> pair in same band
    int g1 = g0 + 1;

    // row g -> band = g/96, r = g%96 ; band = b*5+nb
    // offset = ((b*96 + r)*5 + nb)*2048
    int band = g0 / RR, r0 = g0 % RR;
    int b = band / 5, nb = band % 5;
    size_t base0 = ((size_t)(b * RR + r0) * 5 + nb) * TT;
    size_t base1 = base0 + (size_t)5 * TT;   // next row, same band/nb

    double s0 = 0, s1 = 0, q0 = 0, q1 = 0, m0 = 0, m1 = 0;
    for (int c = 0; c < 8; c++) {
        int i = t + c * 256;
        float af = wc[base0 + i];
        float bf = wc[base1 + i];
        re[i] = af; im[i] = bf;
        double a = (double)af, bb = (double)bf;
        s0 += a; s1 += bb;
        q0 += a * a; q1 += bb * bb;
        m0 = fmax(m0, fabs(a)); m1 = fmax(m1, fabs(bb));
    }
    __syncthreads();

    double SUM0 = blockReduceSum(s0, sred);
    double SUM1 = blockReduceSum(s1, sred);
    double SQ0  = blockReduceSum(q0, sred);
    double SQ1  = blockReduceSum(q1, sred);
    double MX0  = blockReduceMax(m0, sred);
    double MX1  = blockReduceMax(m1, sred);

    // bit-reverse permutation (11 bits)
    for (int c = 0; c < 8; c++) {
        int i = t + c * 256;
        int j = (int)(__brev((unsigned)i) >> 21);
        if (j > i) {
            float tr = re[i]; re[i] = re[j]; re[j] = tr;
            float ti = im[i]; im[i] = im[j]; im[j] = ti;
        }
    }
    __syncthreads();

    // radix-2 DIT stages (fp32)
    for (int s = 1; s <= 11; s++) {
        int half = 1 << (s - 1);
        int m = 1 << s;
        for (int c = 0; c < 4; c++) {
            int bfly = t + c * 256;        // 0..1023
            int grp = bfly >> (s - 1);
            int pos = bfly & (half - 1);
            int i = grp * m + pos;
            int j = i + half;
            int k = pos << (11 - s);
            float wr = tw[2 * k], wi = tw[2 * k + 1];
            float xr = re[j], xi = im[j];
            float tr = wr * xr - wi * xi;
            float ti = wr * xi + wi * xr;
            float ur = re[i], ui = im[i];
            re[j] = ur - tr; im[j] = ui - ti;
            re[i] = ur + tr; im[i] = ui + ti;
        }
        __syncthreads();
    }

    // unpack two real spectra from packed complex FFT; power spectrum k=0..1023
    float psa[4], psb[4];
    for (int c = 0; c < 4; c++) {
        int k = t + c * 256;               // 0..1023
        int j = (TT - k) & (TT - 1);
        float ar = re[k], ai = im[k];
        float br = re[j], bi = im[j];
        float x1r = 0.5f * (ar + br), x1i = 0.5f * (ai - bi);
        float x2r = 0.5f * (ai + bi), x2i = 0.5f * (br - ar);
        psa[c] = x1r * x1r + x1i * x1i;
        psb[c] = x2r * x2r + x2i * x2i;
    }
    __syncthreads();
    for (int c = 0; c < 4; c++) {
        int k = t + c * 256;
        re[k] = psa[c];
        im[k] = psb[c];
    }
    __syncthreads();

    double ls0 = 0, ls1 = 0;
    for (int c = 0; c < 4; c++) {
        ls0 += (double)psa[c]; ls1 += (double)psb[c];
    }
    double S0 = blockReduceSum(ls0, sred);
    double S1 = blockReduceSum(ls1, sred);
    if (S0 == 0.0) S0 = 1.0;
    if (S1 == 0.0) S1 = 1.0;
    float S0f = (float)S0, S1f = (float)S1;

    double e0 = 0, e1 = 0;
    for (int c = 0; c < 4; c++) {
        int k = t + c * 256;
        float p0 = re[k] / S0f, p1 = im[k] / S1f;
        e0 += (double)(p0 * logf(p0 + 1e-10f));
        e1 += (double)(p1 * logf(p1 + 1e-10f));
    }
    double E0 = blockReduceSum(e0, sred);
    double E1 = blockReduceSum(e1, sred);

    if (t == 0) {
        double mean0 = SUM0 / (double)TT;
        double mean1 = SUM1 / (double)TT;
        double nsq0 = SQ0 - (double)TT * mean0 * mean0; if (nsq0 < 0) nsq0 = 0;
        double nsq1 = SQ1 - (double)TT * mean1 * mean1; if (nsq1 < 0) nsq1 = 0;
        double* o0 = rowstats + (size_t)g0 * 6;
        double* o1 = rowstats + (size_t)g1 * 6;
        double n0 = sqrt(nsq0), n1 = sqrt(nsq1);
        o0[0] = mean0; o0[1] = (n0 == 0.0 ? 1.0 : n0); o0[2] = sqrt(nsq0 / 2047.0);
        o0[3] = SQ0;   o0[4] = MX0;                    o0[5] = -E0;
        o1[0] = mean1; o1[1] = (n1 == 0.0 ? 1.0 : n1); o1[2] = sqrt(nsq1 / 2047.0);
        o1[3] = SQ1;   o1[4] = MX1;                    o1[5] = -E1;
    }
}

// ---------- K2: Gram -> correlation matrix C (fp32 accum, fp64 normalize) ----------
// grid = NBANDS * 3 ; block computes rows [tile*32, tile*32+32) x all 96 cols.
// LDS layout k-major Bs[k][row], ld=102 (even pad -> b64-aligned reads, ~2-4 way
// write aliasing only). Each thread: 2 rows x 6 cols, fp32 fmac.
#define KB 64
#define LD 102
__global__ __launch_bounds__(256) void gram_kernel(
    const float* __restrict__ wc, const double* __restrict__ rowstats,
    float* __restrict__ C)
{
    __shared__ float Bs[KB][LD];
    int band = blockIdx.x / 3, tile = blockIdx.x % 3;
    int b = band / 5, nb = band % 5;
    size_t bandbase = ((size_t)b * RR * 5 + nb) * TT;   // + r*5*2048

    int t = threadIdx.x;
    int ty = t >> 4;           // 0..15 -> row pair in tile
    int tx = t & 15;           // 0..15 -> col group
    int row0 = tile * 32 + ty * 2;
    int c0 = tx * 6;

    float acc[2][6];
#pragma unroll
    for (int i = 0; i < 2; i++)
#pragma unroll
        for (int j = 0; j < 6; j++) acc[i][j] = 0.0f;

    for (int k0 = 0; k0 < TT; k0 += KB) {
        // stage: 96 rows x KB floats, transposed to k-major
        for (int idx = t; idx < RR * (KB / 4); idx += 256) {
            int r = idx >> 4, k4 = idx & 15;
            float4 v = *(const float4*)(wc + bandbase + (size_t)r * (5 * TT) + k0 + k4 * 4);
            Bs[k4 * 4 + 0][r] = v.x; Bs[k4 * 4 + 1][r] = v.y;
            Bs[k4 * 4 + 2][r] = v.z; Bs[k4 * 4 + 3][r] = v.w;
        }
        __syncthreads();
#pragma unroll 4
        for (int kk = 0; kk < KB; kk++) {
            float2 a  = *(const float2*)&Bs[kk][row0];
            float2 b0 = *(const float2*)&Bs[kk][c0];
            float2 b1 = *(const float2*)&Bs[kk][c0 + 2];
            float2 b2 = *(const float2*)&Bs[kk][c0 + 4];
            float bv[6] = {b0.x, b0.y, b1.x, b1.y, b2.x, b2.y};
#pragma unroll
            for (int j = 0; j < 6; j++) {
                acc[0][j] = fmaf(a.x, bv[j], acc[0][j]);
                acc[1][j] = fmaf(a.y, bv[j], acc[1][j]);
            }
        }
        __syncthreads();
    }

#pragma unroll
    for (int i = 0; i < 2; i++) {
        int row = row0 + i;
        const double* rsi = rowstats + (size_t)(band * RR + row) * 6;
        double mu_i = rsi[0], nm_i = rsi[1];
#pragma unroll
        for (int j = 0; j < 6; j++) {
            int col = c0 + j;
            const double* rsj = rowstats + (size_t)(band * RR + col) * 6;
            double mu_j = rsj[0], nm_j = rsj[1];
            double c = ((double)acc[i][j] - (double)TT * mu_i * mu_j) / (nm_i * nm_j);
            if (row == col) c = 0.0;
            C[(size_t)band * (RR * RR) + (size_t)row * RR + col] = (float)c;
        }
    }
}

// ---------- K3: per-band 0.8-quantile of |C[tril]| via LDS histogram select ----------
__global__ __launch_bounds__(256) void quantile_kernel(
    const float* __restrict__ C, double* __restrict__ thr)
{
    __shared__ int hist[NBIN];
    __shared__ int chunk[256];
    __shared__ float cand[MAXCAND];
    __shared__ int ctrl[4];   // B0, B1, cumB0, ncand

    int band = blockIdx.x, t = threadIdx.x;
    const float* Cb = C + (size_t)band * (RR * RR);

    for (int i = t; i < NBIN; i += 256) hist[i] = 0;
    if (t == 0) ctrl[3] = 0;
    __syncthreads();

    for (int idx = t; idx < RR * RR; idx += 256) {
        int i = idx / RR, j = idx % RR;
        if (j < i) {
            float val = fabsf(Cb[idx]);
            int bin = (int)(val * (float)NBIN);
            bin = bin > (NBIN - 1) ? (NBIN - 1) : bin;
            atomicAdd(&hist[bin], 1);
        }
    }
    __syncthreads();

    int cs = 0;
    for (int i = 0; i < 64; i++) cs += hist[t * 64 + i];
    chunk[t] = cs;
    __syncthreads();

    if (t == 0) {
        // find bins holding ascending ranks 3647 and 3648 (0-based)
        int r0 = 3647, r1 = 3648;
        int cum = 0, c0 = 0;
        while (c0 < 256 && cum + chunk[c0] <= r0) { cum += chunk[c0]; c0++; }
        int bin = c0 * 64, cb = cum;
        while (cb + hist[bin] <= r0) { cb += hist[bin]; bin++; }
        int B0 = bin, cumB0 = cb;
        // continue for r1
        int bin1 = bin, cb1 = cb;
        while (cb1 + hist[bin1] <= r1) { cb1 += hist[bin1]; bin1++; }
        ctrl[0] = B0; ctrl[1] = bin1; ctrl[2] = cumB0;
    }
    __syncthreads();

    int B0 = ctrl[0], B1 = ctrl[1];
    for (int idx = t; idx < RR * RR; idx += 256) {
        int i = idx / RR, j = idx % RR;
        if (j < i) {
            float val = fabsf(Cb[idx]);
            int bin = (int)(val * (float)NBIN);
            bin = bin > (NBIN - 1) ? (NBIN - 1) : bin;
            if (bin >= B0 && bin <= B1) {
                int k = atomicAdd(&ctrl[3], 1);
                if (k < MAXCAND) cand[k] = val;
            }
        }
    }
    __syncthreads();

    if (t == 0) {
        int n = ctrl[3]; if (n > MAXCAND) n = MAXCAND;
        // insertion sort (n is ~10-30 for this data)
        for (int i = 1; i < n; i++) {
            float key = cand[i]; int j = i - 1;
            while (j >= 0 && cand[j] > key) { cand[j + 1] = cand[j]; j--; }
            cand[j + 1] = key;
        }
        int r0 = 3647 - ctrl[2];
        int r1 = 3648 - ctrl[2];
        double v0 = (double)cand[r0], v1 = (double)cand[r1];
        thr[band] = v0 + 0.2 * (v1 - v0);   // pos = 0.8*(4560-1) = 3647.2
    }
}

// ---------- K4: graph props + node features + MLP; masks A in place, writes F ----------
__global__ __launch_bounds__(256) void graph_feat_kernel(
    const double* __restrict__ thrA,
    const double* __restrict__ rowstats, const int* __restrict__ community,
    const float* __restrict__ W1, const float* __restrict__ b1,
    const float* __restrict__ W2, const float* __restrict__ b2,
    float* __restrict__ A_out, float* __restrict__ F_out)
{
    __shared__ unsigned char Bm[RR][RR];
    __shared__ unsigned long long msk[RR][2];
    __shared__ int deg[RR];
    __shared__ double sred[8];
    __shared__ double feat[11];
    __shared__ double h[32];

    int band = blockIdx.x, t = threadIdx.x;
    double thr = thrA[band];
    float* Ab = A_out + (size_t)band * (RR * RR);

    for (int idx = t; idx < RR * RR; idx += 256) {
        float c = Ab[idx];
        bool keep = ((double)fabsf(c) >= thr);
        Bm[idx / RR][idx % RR] = (keep && c != 0.0f) ? 1 : 0;
        Ab[idx] = keep ? c : 0.0f;
    }
    __syncthreads();

    if (t < RR) {
        unsigned long long m0 = 0, m1 = 0; int d = 0;
        for (int j = 0; j < RR; j++) {
            if (Bm[t][j]) { d++; if (j < 64) m0 |= (1ull << j); else m1 |= (1ull << (j - 64)); }
        }
        msk[t][0] = m0; msk[t][1] = m1; deg[t] = d;
    }
    __syncthreads();

    double triord = 0, ein = 0, expin = 0;
    for (int idx = t; idx < RR * RR; idx += 256) {
        int i = idx / RR, j = idx % RR;
        if (Bm[i][j])
            triord += (double)(__popcll(msk[i][0] & msk[j][0]) +
                               __popcll(msk[i][1] & msk[j][1]));
        if (i != j && community[i] == community[j]) {
            ein += (double)Bm[i][j];
            expin += (double)deg[i] * (double)deg[j];
        }
    }
    double TRI   = blockReduceSum(triord, sred);
    double EIN   = blockReduceSum(ein, sred);
    double EXPIN = blockReduceSum(expin, sred);
    double dv = (t < RR) ? (double)deg[t] : 0.0;
    double DEGS = blockReduceSum(dv, sred);
    double POSS2 = blockReduceSum((t < RR) ? dv * (dv - 1.0) : 0.0, sred);

    const double* rs = rowstats + (size_t)band * RR * 6;
    double N0 = blockReduceSum((t < RR) ? rs[t * 6 + 0] : 0.0, sred); // mean
    double N1 = blockReduceSum((t < RR) ? rs[t * 6 + 2] : 0.0, sred); // std
    double N2 = blockReduceSum((t < RR) ? rs[t * 6 + 3] : 0.0, sred); // energy
    double N3 = blockReduceSum((t < RR) ? rs[t * 6 + 4] : 0.0, sred); // maxamp
    double N4 = blockReduceSum((t < RR) ? rs[t * 6 + 5] : 0.0, sred); // ent

    if (t == 0) {
        double ne = 0.5 * DEGS;
        feat[0] = N0 / (double)RR;
        feat[1] = N1 / (double)RR;
        feat[2] = N2 / (double)RR;
        feat[3] = N3 / (double)RR;
        feat[4] = N4 / (double)RR;
        feat[5] = ne;
        feat[6] = ne / (double)NTRIL;
        feat[7] = DEGS / (double)RR;
        double tri = TRI / 6.0, poss = POSS2 * 0.5;
        feat[8] = (poss > 0.0) ? tri / poss : 0.0;
        feat[9] = ((double)RR + DEGS) / ((double)RR * (double)(RR - 1));
        double m2 = DEGS;
        feat[10] = (m2 > 0.0) ? (EIN - EXPIN / m2) / m2 : 0.0;
    }
    __syncthreads();

    if (t < 32) {
        double a = (double)b1[t];
        for (int k = 0; k < 11; k++) a += (double)W1[t * 11 + k] * feat[k];
        h[t] = (a > 0.0) ? a : 0.0;
    }
    __syncthreads();
    if (t < 64) {
        double a = (double)b2[t];
        for (int j = 0; j < 32; j++) a += (double)W2[t * 32 + j] * h[j];
        F_out[(size_t)band * 64 + t] = (float)a;
    }
}

extern "C" void kernel_launch(void* const* d_in, const int* in_sizes, int n_in,
                              void* d_out, int out_size, void* d_ws, size_t ws_size,
                              hipStream_t stream) {
    const float* wc        = (const float*)d_in[0];
    // d_in[1] frequency_bands: unused by the reference math
    const int*   community = (const int*)d_in[2];
    const float* W1        = (const float*)d_in[3];
    const float* b1        = (const float*)d_in[4];
    const float* W2        = (const float*)d_in[5];
    const float* b2        = (const float*)d_in[6];

    float* A_out = (float*)d_out;          // C staged here fp32, then masked in place
    float* F_out = A_out + A_ELEMS;

    // workspace: tw 8192 B | rowstats 15360*6*8 = 737280 B | thr 160*8 B  => ~746 KB
    char* ws = (char*)d_ws;
    float*  tw       = (float*)ws;
    double* rowstats = (double*)(ws + 8192);
    double* thr      = (double*)(ws + 8192 + 737280);

    hipLaunchKernelGGL(twiddle_kernel, dim3(4), dim3(256), 0, stream, tw);
    hipLaunchKernelGGL(rowstat_fft_kernel, dim3(NBANDS * RR / 2), dim3(256), 0, stream,
                       wc, tw, rowstats);
    hipLaunchKernelGGL(gram_kernel, dim3(NBANDS * 3), dim3(256), 0, stream,
                       wc, rowstats, A_out);
    hipLaunchKernelGGL(quantile_kernel, dim3(NBANDS), dim3(256), 0, stream, A_out, thr);
    hipLaunchKernelGGL(graph_feat_kernel, dim3(NBANDS), dim3(256), 0, stream,
                       thr, rowstats, community, W1, b1, W2, b2, A_out, F_out);
}

// Round 4
// 463.865 us; speedup vs baseline: 1.7452x; 1.1523x over previous
//
#include <hip/hip_runtime.h>
#include <hip/hip_bf16.h>
#include <math.h>
#include <float.h>

#ifndef M_PI
#define M_PI 3.14159265358979323846
#endif

// Problem constants
#define NBANDS 160      // B*NB = 32*5
#define RR 96           // rows per band
#define TT 2048         // time samples
#define NTRIL 4560      // 96*95/2
#define A_ELEMS ((size_t)NBANDS * RR * RR)
#define NBIN 16384
#define MAXCAND 512

// XOR bank swizzle: bijective within [0,2048); makes all FFT exchange
// patterns <=2-way (free) — verified rank-5 lane->bank maps for each pass.
#define PHI(L) ((L) ^ (((L) >> 5) & 31))

// ---------- block reductions (256 threads) ----------
__device__ inline double blockReduceSum(double v, double* sred) {
    for (int off = 32; off > 0; off >>= 1) v += __shfl_down(v, off, 64);
    int lane = threadIdx.x & 63, wid = threadIdx.x >> 6;
    if (lane == 0) sred[wid] = v;
    __syncthreads();
    int nw = (blockDim.x + 63) >> 6;
    if (threadIdx.x == 0) {
        double r = sred[0];
        for (int i = 1; i < nw; i++) r += sred[i];
        sred[0] = r;
    }
    __syncthreads();
    double r = sred[0];
    __syncthreads();
    return r;
}

__device__ inline double blockReduceMax(double v, double* sred) {
    for (int off = 32; off > 0; off >>= 1) v = fmax(v, __shfl_down(v, off, 64));
    int lane = threadIdx.x & 63, wid = threadIdx.x >> 6;
    if (lane == 0) sred[wid] = v;
    __syncthreads();
    int nw = (blockDim.x + 63) >> 6;
    if (threadIdx.x == 0) {
        double r = sred[0];
        for (int i = 1; i < nw; i++) r = fmax(r, sred[i]);
        sred[0] = r;
    }
    __syncthreads();
    double r = sred[0];
    __syncthreads();
    return r;
}

// ---------- K0: twiddle table  tw[k] = exp(-2*pi*i*k/2048), k<1024 (fp32) ----------
__global__ void twiddle_kernel(float* tw) {
    int k = blockIdx.x * blockDim.x + threadIdx.x;
    if (k < 1024) {
        double ang = -2.0 * M_PI * (double)k / 2048.0;
        tw[2 * k]     = (float)cos(ang);
        tw[2 * k + 1] = (float)sin(ang);
    }
}

// DIT butterfly on register pair (r1, r2) with twiddle (WR, WI)
#define BFLY(r1, r2, WR, WI) do { \
    float _wr = (WR), _wi = (WI); \
    float _tr = _wr * yr[r2] - _wi * yi[r2]; \
    float _ti = _wr * yi[r2] + _wi * yr[r2]; \
    yr[r2] = yr[r1] - _tr; yi[r2] = yi[r1] - _ti; \
    yr[r1] += _tr; yi[r1] += _ti; } while (0)

// ---------- K1: per-row stats + fp32 register radix-8 FFT entropy ----------
// Two real rows packed into one complex 2048-pt FFT per block.
// 4 register passes (stages 1-3, 4-6, 7-8, 9-11); LDS only for exchanges,
// all conflict-free via PHI swizzle. Output in natural order -> partner
// (k, N-k) unpack is a consecutive read. Half-spectrum sums via symmetry.
// rowstats layout per row g: [mean, norm_guarded, std, energy, maxamp, ent]
__global__ __launch_bounds__(256) void rowstat_fft_kernel(
    const float* __restrict__ wc, const float* __restrict__ tw,
    double* __restrict__ rowstats)
{
    __shared__ float re[TT];
    __shared__ float im[TT];
    __shared__ double sred[8];
    __shared__ float bcast[4];

    int t = threadIdx.x;
    int g0 = blockIdx.x * 2;          // global row index (even); pair in same band
    int g1 = g0 + 1;

    int band = g0 / RR, r0 = g0 % RR;
    int b = band / 5, nb = band % 5;
    size_t base0 = ((size_t)(b * RR + r0) * 5 + nb) * TT;
    size_t base1 = base0 + (size_t)5 * TT;   // next row, same band/nb

    // coalesced load + stats; store natural order at PHI
    double s0 = 0, s1 = 0, q0 = 0, q1 = 0, m0 = 0, m1 = 0;
#pragma unroll
    for (int c = 0; c < 8; c++) {
        int i = t + c * 256;
        float af = wc[base0 + i];
        float bf = wc[base1 + i];
        int P = PHI(i);
        re[P] = af; im[P] = bf;
        double a = (double)af, bb = (double)bf;
        s0 += a; s1 += bb;
        q0 += a * a; q1 += bb * bb;
        m0 = fmax(m0, fabs(a)); m1 = fmax(m1, fabs(bb));
    }
    __syncthreads();

    double SUM0 = blockReduceSum(s0, sred);
    double SUM1 = blockReduceSum(s1, sred);
    double SQ0  = blockReduceSum(q0, sred);
    double SQ1  = blockReduceSum(q1, sred);
    double MX0  = blockReduceMax(m0, sred);
    double MX1  = blockReduceMax(m1, sred);

    float yr[8], yi[8];

    // X0: bit-reversed gather -> regs hold positions 8t+j of the DIT array
#pragma unroll
    for (int j = 0; j < 8; j++) {
        int p = 8 * t + j;
        int L = (int)(__brev((unsigned)p) >> 21);
        int P = PHI(L);
        yr[j] = re[P]; yi[j] = im[P];
    }

    // P1: stages 1-3 (radix-8 within consecutive 8-block), hardcoded twiddles
    const float RC = 0.70710678f;
    BFLY(0, 1, 1.0f, 0.0f); BFLY(2, 3, 1.0f, 0.0f);
    BFLY(4, 5, 1.0f, 0.0f); BFLY(6, 7, 1.0f, 0.0f);
    BFLY(0, 2, 1.0f, 0.0f); BFLY(1, 3, 0.0f, -1.0f);
    BFLY(4, 6, 1.0f, 0.0f); BFLY(5, 7, 0.0f, -1.0f);
    BFLY(0, 4, 1.0f, 0.0f); BFLY(1, 5, RC, -RC);
    BFLY(2, 6, 0.0f, -1.0f); BFLY(3, 7, -RC, -RC);

    // X1: write positions 8t+j, read positions 64*bb + 8k + o
    __syncthreads();
#pragma unroll
    for (int j = 0; j < 8; j++) {
        int P = PHI(8 * t + j);
        re[P] = yr[j]; im[P] = yi[j];
    }
    __syncthreads();
    int oo = t & 7;
    int bb64 = 4 * ((t >> 3) & 7) + (t >> 6);   // bijective, bank-friendly
#pragma unroll
    for (int k = 0; k < 8; k++) {
        int P = PHI(64 * bb64 + 8 * k + oo);
        yr[k] = re[P]; yi[k] = im[P];
    }

    // P2: stages 4-6 (strides 8,16,32); pos depends on oo
    {
        int k0 = oo << 7;
        float w0r = tw[2 * k0], w0i = tw[2 * k0 + 1];
        BFLY(0, 1, w0r, w0i); BFLY(2, 3, w0r, w0i);
        BFLY(4, 5, w0r, w0i); BFLY(6, 7, w0r, w0i);
        int ka = oo << 6, kb = (oo + 8) << 6;
        float war = tw[2 * ka], wai = tw[2 * ka + 1];
        float wbr = tw[2 * kb], wbi = tw[2 * kb + 1];
        BFLY(0, 2, war, wai); BFLY(1, 3, wbr, wbi);
        BFLY(4, 6, war, wai); BFLY(5, 7, wbr, wbi);
        int kc0 = oo << 5, kc1 = (oo + 8) << 5, kc2 = (oo + 16) << 5, kc3 = (oo + 24) << 5;
        BFLY(0, 4, tw[2 * kc0], tw[2 * kc0 + 1]);
        BFLY(1, 5, tw[2 * kc1], tw[2 * kc1 + 1]);
        BFLY(2, 6, tw[2 * kc2], tw[2 * kc2 + 1]);
        BFLY(3, 7, tw[2 * kc3], tw[2 * kc3 + 1]);
    }

    // X2: write positions 64*bb + 8k + oo, read positions 256*B3 + 64k + O3
    __syncthreads();
#pragma unroll
    for (int k = 0; k < 8; k++) {
        int P = PHI(64 * bb64 + 8 * k + oo);
        re[P] = yr[k]; im[P] = yi[k];
    }
    __syncthreads();
    int O3 = t & 63, Wq = t >> 6;
#pragma unroll
    for (int s = 0; s < 2; s++) {
        int B3 = Wq + 4 * s;
#pragma unroll
        for (int k = 0; k < 4; k++) {
            int P = PHI(256 * B3 + 64 * k + O3);
            yr[4 * s + k] = re[P]; yi[4 * s + k] = im[P];
        }
    }

    // P3: stages 7-8 (radix-4, strides 64,128) on two groups of 4 regs
    {
        int kt = O3 << 4;
        float w0r = tw[2 * kt], w0i = tw[2 * kt + 1];
        int ka = O3 << 3, kb = (O3 + 64) << 3;
        float war = tw[2 * ka], wai = tw[2 * ka + 1];
        float wbr = tw[2 * kb], wbi = tw[2 * kb + 1];
        BFLY(0, 1, w0r, w0i); BFLY(2, 3, w0r, w0i);
        BFLY(4, 5, w0r, w0i); BFLY(6, 7, w0r, w0i);
        BFLY(0, 2, war, wai); BFLY(1, 3, wbr, wbi);
        BFLY(4, 6, war, wai); BFLY(5, 7, wbr, wbi);
    }

    // X3: write positions 256*B3 + 64k + O3, read positions 256k + t
    __syncthreads();
#pragma unroll
    for (int s = 0; s < 2; s++) {
        int B3 = Wq + 4 * s;
#pragma unroll
        for (int k = 0; k < 4; k++) {
            int P = PHI(256 * B3 + 64 * k + O3);
            re[P] = yr[4 * s + k]; im[P] = yi[4 * s + k];
        }
    }
    __syncthreads();
#pragma unroll
    for (int k = 0; k < 8; k++) {
        int P = PHI(256 * k + t);
        yr[k] = re[P]; yi[k] = im[P];
    }

    // P4: stages 9-11 (strides 256,512,1024); pos depends on t
    {
        int k9 = t << 2;
        float w0r = tw[2 * k9], w0i = tw[2 * k9 + 1];
        BFLY(0, 1, w0r, w0i); BFLY(2, 3, w0r, w0i);
        BFLY(4, 5, w0r, w0i); BFLY(6, 7, w0r, w0i);
        int ka = t << 1, kb = (t + 256) << 1;
        float war = tw[2 * ka], wai = tw[2 * ka + 1];
        float wbr = tw[2 * kb], wbi = tw[2 * kb + 1];
        BFLY(0, 2, war, wai); BFLY(1, 3, wbr, wbi);
        BFLY(4, 6, war, wai); BFLY(5, 7, wbr, wbi);
        BFLY(0, 4, tw[2 * t], tw[2 * t + 1]);
        BFLY(1, 5, tw[2 * (t + 256)], tw[2 * (t + 256) + 1]);
        BFLY(2, 6, tw[2 * (t + 512)], tw[2 * (t + 512) + 1]);
        BFLY(3, 7, tw[2 * (t + 768)], tw[2 * (t + 768) + 1]);
    }
    // regs now hold X[256k + t] in NATURAL order

    // X-final: write natural order; partner read (2048 - p) is consecutive
    __syncthreads();
#pragma unroll
    for (int k = 0; k < 8; k++) {
        int P = PHI(256 * k + t);
        re[P] = yr[k]; im[P] = yi[k];
    }
    __syncthreads();

    float psa[8], psb[8];
#pragma unroll
    for (int k = 0; k < 8; k++) {
        int q = (2048 - t - 256 * k) & 2047;
        int P = PHI(q);
        float prr = re[P], pii = im[P];
        float sr = yr[k] + prr, di = yi[k] - pii;   // row a: (X + conj(Xq))/2
        float si = yi[k] + pii, dr = yr[k] - prr;   // row b: (X - conj(Xq))/(2i)
        psa[k] = 0.25f * (sr * sr + di * di);
        psb[k] = 0.25f * (si * si + dr * dr);
    }

    // half-spectrum sums via symmetry: sum_{0..1023} = (sum_all + ps[0] - ps[1024])/2
    double la = 0, lb = 0;
#pragma unroll
    for (int k = 0; k < 8; k++) { la += (double)psa[k]; lb += (double)psb[k]; }
    double SAall = blockReduceSum(la, sred);
    double SBall = blockReduceSum(lb, sred);
    if (t == 0) {   // thread 0 holds positions 0 (k=0) and 1024 (k=4)
        bcast[0] = psa[0]; bcast[1] = psa[4];
        bcast[2] = psb[0]; bcast[3] = psb[4];
    }
    __syncthreads();
    double Sa = 0.5 * (SAall + (double)bcast[0] - (double)bcast[1]);
    double Sb = 0.5 * (SBall + (double)bcast[2] - (double)bcast[3]);
    if (Sa == 0.0) Sa = 1.0;
    if (Sb == 0.0) Sb = 1.0;
    float invSa = (float)(1.0 / Sa), invSb = (float)(1.0 / Sb);

    double ea = 0, eb = 0;
#pragma unroll
    for (int k = 0; k < 8; k++) {
        float pa = psa[k] * invSa;
        float pb = psb[k] * invSb;
        ea += (double)(pa * logf(pa + 1e-10f));
        eb += (double)(pb * logf(pb + 1e-10f));
    }
    double EAall = blockReduceSum(ea, sred);
    double EBall = blockReduceSum(eb, sred);

    if (t == 0) {
        float pa0 = psa[0] * invSa, pa4 = psa[4] * invSa;
        float pb0 = psb[0] * invSb, pb4 = psb[4] * invSb;
        double TA = 0.5 * (EAall + (double)(pa0 * logf(pa0 + 1e-10f))
                                 - (double)(pa4 * logf(pa4 + 1e-10f)));
        double TB = 0.5 * (EBall + (double)(pb0 * logf(pb0 + 1e-10f))
                                 - (double)(pb4 * logf(pb4 + 1e-10f)));
        double mean0 = SUM0 / (double)TT;
        double mean1 = SUM1 / (double)TT;
        double nsq0 = SQ0 - (double)TT * mean0 * mean0; if (nsq0 < 0) nsq0 = 0;
        double nsq1 = SQ1 - (double)TT * mean1 * mean1; if (nsq1 < 0) nsq1 = 0;
        double* w0 = rowstats + (size_t)g0 * 6;
        double* w1 = rowstats + (size_t)g1 * 6;
        double n0 = sqrt(nsq0), n1 = sqrt(nsq1);
        w0[0] = mean0; w0[1] = (n0 == 0.0 ? 1.0 : n0); w0[2] = sqrt(nsq0 / 2047.0);
        w0[3] = SQ0;   w0[4] = MX0;                    w0[5] = -TA;
        w1[0] = mean1; w1[1] = (n1 == 0.0 ? 1.0 : n1); w1[2] = sqrt(nsq1 / 2047.0);
        w1[3] = SQ1;   w1[4] = MX1;                    w1[5] = -TB;
    }
}

// ---------- K2: Gram -> correlation matrix C (fp32 accum, fp64 normalize) ----------
#define KB 64
#define LD 102
__global__ __launch_bounds__(256) void gram_kernel(
    const float* __restrict__ wc, const double* __restrict__ rowstats,
    float* __restrict__ C)
{
    __shared__ float Bs[KB][LD];
    int band = blockIdx.x / 3, tile = blockIdx.x % 3;
    int b = band / 5, nb = band % 5;
    size_t bandbase = ((size_t)b * RR * 5 + nb) * TT;   // + r*5*2048

    int t = threadIdx.x;
    int ty = t >> 4;           // 0..15 -> row pair in tile
    int tx = t & 15;           // 0..15 -> col group
    int row0 = tile * 32 + ty * 2;
    int c0 = tx * 6;

    float acc[2][6];
#pragma unroll
    for (int i = 0; i < 2; i++)
#pragma unroll
        for (int j = 0; j < 6; j++) acc[i][j] = 0.0f;

    for (int k0 = 0; k0 < TT; k0 += KB) {
        for (int idx = t; idx < RR * (KB / 4); idx += 256) {
            int r = idx >> 4, k4 = idx & 15;
            float4 v = *(const float4*)(wc + bandbase + (size_t)r * (5 * TT) + k0 + k4 * 4);
            Bs[k4 * 4 + 0][r] = v.x; Bs[k4 * 4 + 1][r] = v.y;
            Bs[k4 * 4 + 2][r] = v.z; Bs[k4 * 4 + 3][r] = v.w;
        }
        __syncthreads();
#pragma unroll 4
        for (int kk = 0; kk < KB; kk++) {
            float2 a  = *(const float2*)&Bs[kk][row0];
            float2 b0 = *(const float2*)&Bs[kk][c0];
            float2 b1 = *(const float2*)&Bs[kk][c0 + 2];
            float2 b2 = *(const float2*)&Bs[kk][c0 + 4];
            float bv[6] = {b0.x, b0.y, b1.x, b1.y, b2.x, b2.y};
#pragma unroll
            for (int j = 0; j < 6; j++) {
                acc[0][j] = fmaf(a.x, bv[j], acc[0][j]);
                acc[1][j] = fmaf(a.y, bv[j], acc[1][j]);
            }
        }
        __syncthreads();
    }

#pragma unroll
    for (int i = 0; i < 2; i++) {
        int row = row0 + i;
        const double* rsi = rowstats + (size_t)(band * RR + row) * 6;
        double mu_i = rsi[0], nm_i = rsi[1];
#pragma unroll
        for (int j = 0; j < 6; j++) {
            int col = c0 + j;
            const double* rsj = rowstats + (size_t)(band * RR + col) * 6;
            double mu_j = rsj[0], nm_j = rsj[1];
            double c = ((double)acc[i][j] - (double)TT * mu_i * mu_j) / (nm_i * nm_j);
            if (row == col) c = 0.0;
            C[(size_t)band * (RR * RR) + (size_t)row * RR + col] = (float)c;
        }
    }
}

// ---------- K3: per-band 0.8-quantile of |C[tril]| via LDS histogram select ----------
__global__ __launch_bounds__(256) void quantile_kernel(
    const float* __restrict__ C, double* __restrict__ thr)
{
    __shared__ int hist[NBIN];
    __shared__ int chunk[256];
    __shared__ float cand[MAXCAND];
    __shared__ int ctrl[4];   // B0, B1, cumB0, ncand

    int band = blockIdx.x, t = threadIdx.x;
    const float* Cb = C + (size_t)band * (RR * RR);

    for (int i = t; i < NBIN; i += 256) hist[i] = 0;
    if (t == 0) ctrl[3] = 0;
    __syncthreads();

    for (int idx = t; idx < RR * RR; idx += 256) {
        int i = idx / RR, j = idx % RR;
        if (j < i) {
            float val = fabsf(Cb[idx]);
            int bin = (int)(val * (float)NBIN);
            bin = bin > (NBIN - 1) ? (NBIN - 1) : bin;
            atomicAdd(&hist[bin], 1);
        }
    }
    __syncthreads();

    int cs = 0;
    for (int i = 0; i < 64; i++) cs += hist[t * 64 + i];
    chunk[t] = cs;
    __syncthreads();

    if (t == 0) {
        int r0 = 3647, r1 = 3648;
        int cum = 0, c0 = 0;
        while (c0 < 256 && cum + chunk[c0] <= r0) { cum += chunk[c0]; c0++; }
        int bin = c0 * 64, cb = cum;
        while (cb + hist[bin] <= r0) { cb += hist[bin]; bin++; }
        int B0 = bin, cumB0 = cb;
        int bin1 = bin, cb1 = cb;
        while (cb1 + hist[bin1] <= r1) { cb1 += hist[bin1]; bin1++; }
        ctrl[0] = B0; ctrl[1] = bin1; ctrl[2] = cumB0;
    }
    __syncthreads();

    int B0 = ctrl[0], B1 = ctrl[1];
    for (int idx = t; idx < RR * RR; idx += 256) {
        int i = idx / RR, j = idx % RR;
        if (j < i) {
            float val = fabsf(Cb[idx]);
            int bin = (int)(val * (float)NBIN);
            bin = bin > (NBIN - 1) ? (NBIN - 1) : bin;
            if (bin >= B0 && bin <= B1) {
                int k = atomicAdd(&ctrl[3], 1);
                if (k < MAXCAND) cand[k] = val;
            }
        }
    }
    __syncthreads();

    if (t == 0) {
        int n = ctrl[3]; if (n > MAXCAND) n = MAXCAND;
        for (int i = 1; i < n; i++) {
            float key = cand[i]; int j = i - 1;
            while (j >= 0 && cand[j] > key) { cand[j + 1] = cand[j]; j--; }
            cand[j + 1] = key;
        }
        int r0 = 3647 - ctrl[2];
        int r1 = 3648 - ctrl[2];
        double v0 = (double)cand[r0], v1 = (double)cand[r1];
        thr[band] = v0 + 0.2 * (v1 - v0);   // pos = 0.8*(4560-1) = 3647.2
    }
}

// ---------- K4: graph props + node features + MLP; masks A in place, writes F ----------
__global__ __launch_bounds__(256) void graph_feat_kernel(
    const double* __restrict__ thrA,
    const double* __restrict__ rowstats, const int* __restrict__ community,
    const float* __restrict__ W1, const float* __restrict__ b1,
    const float* __restrict__ W2, const float* __restrict__ b2,
    float* __restrict__ A_out, float* __restrict__ F_out)
{
    __shared__ unsigned char Bm[RR][RR];
    __shared__ unsigned long long msk[RR][2];
    __shared__ int deg[RR];
    __shared__ double sred[8];
    __shared__ double feat[11];
    __shared__ double h[32];

    int band = blockIdx.x, t = threadIdx.x;
    double thr = thrA[band];
    float* Ab = A_out + (size_t)band * (RR * RR);

    for (int idx = t; idx < RR * RR; idx += 256) {
        float c = Ab[idx];
        bool keep = ((double)fabsf(c) >= thr);
        Bm[idx / RR][idx % RR] = (keep && c != 0.0f) ? 1 : 0;
        Ab[idx] = keep ? c : 0.0f;
    }
    __syncthreads();

    if (t < RR) {
        unsigned long long m0 = 0, m1 = 0; int d = 0;
        for (int j = 0; j < RR; j++) {
            if (Bm[t][j]) { d++; if (j < 64) m0 |= (1ull << j); else m1 |= (1ull << (j - 64)); }
        }
        msk[t][0] = m0; msk[t][1] = m1; deg[t] = d;
    }
    __syncthreads();

    double triord = 0, ein = 0, expin = 0;
    for (int idx = t; idx < RR * RR; idx += 256) {
        int i = idx / RR, j = idx % RR;
        if (Bm[i][j])
            triord += (double)(__popcll(msk[i][0] & msk[j][0]) +
                               __popcll(msk[i][1] & msk[j][1]));
        if (i != j && community[i] == community[j]) {
            ein += (double)Bm[i][j];
            expin += (double)deg[i] * (double)deg[j];
        }
    }
    double TRI   = blockReduceSum(triord, sred);
    double EIN   = blockReduceSum(ein, sred);
    double EXPIN = blockReduceSum(expin, sred);
    double dv = (t < RR) ? (double)deg[t] : 0.0;
    double DEGS = blockReduceSum(dv, sred);
    double POSS2 = blockReduceSum((t < RR) ? dv * (dv - 1.0) : 0.0, sred);

    const double* rs = rowstats + (size_t)band * RR * 6;
    double N0 = blockReduceSum((t < RR) ? rs[t * 6 + 0] : 0.0, sred); // mean
    double N1 = blockReduceSum((t < RR) ? rs[t * 6 + 2] : 0.0, sred); // std
    double N2 = blockReduceSum((t < RR) ? rs[t * 6 + 3] : 0.0, sred); // energy
    double N3 = blockReduceSum((t < RR) ? rs[t * 6 + 4] : 0.0, sred); // maxamp
    double N4 = blockReduceSum((t < RR) ? rs[t * 6 + 5] : 0.0, sred); // ent

    if (t == 0) {
        double ne = 0.5 * DEGS;
        feat[0] = N0 / (double)RR;
        feat[1] = N1 / (double)RR;
        feat[2] = N2 / (double)RR;
        feat[3] = N3 / (double)RR;
        feat[4] = N4 / (double)RR;
        feat[5] = ne;
        feat[6] = ne / (double)NTRIL;
        feat[7] = DEGS / (double)RR;
        double tri = TRI / 6.0, poss = POSS2 * 0.5;
        feat[8] = (poss > 0.0) ? tri / poss : 0.0;
        feat[9] = ((double)RR + DEGS) / ((double)RR * (double)(RR - 1));
        double m2 = DEGS;
        feat[10] = (m2 > 0.0) ? (EIN - EXPIN / m2) / m2 : 0.0;
    }
    __syncthreads();

    if (t < 32) {
        double a = (double)b1[t];
        for (int k = 0; k < 11; k++) a += (double)W1[t * 11 + k] * feat[k];
        h[t] = (a > 0.0) ? a : 0.0;
    }
    __syncthreads();
    if (t < 64) {
        double a = (double)b2[t];
        for (int j = 0; j < 32; j++) a += (double)W2[t * 32 + j] * h[j];
        F_out[(size_t)band * 64 + t] = (float)a;
    }
}

extern "C" void kernel_launch(void* const* d_in, const int* in_sizes, int n_in,
                              void* d_out, int out_size, void* d_ws, size_t ws_size,
                              hipStream_t stream) {
    const float* wc        = (const float*)d_in[0];
    // d_in[1] frequency_bands: unused by the reference math
    const int*   community = (const int*)d_in[2];
    const float* W1        = (const float*)d_in[3];
    const float* b1        = (const float*)d_in[4];
    const float* W2        = (const float*)d_in[5];
    const float* b2        = (const float*)d_in[6];

    float* A_out = (float*)d_out;          // C staged here fp32, then masked in place
    float* F_out = A_out + A_ELEMS;

    // workspace: tw 8192 B | rowstats 15360*6*8 = 737280 B | thr 160*8 B  => ~746 KB
    char* ws = (char*)d_ws;
    float*  tw       = (float*)ws;
    double* rowstats = (double*)(ws + 8192);
    double* thr      = (double*)(ws + 8192 + 737280);

    hipLaunchKernelGGL(twiddle_kernel, dim3(4), dim3(256), 0, stream, tw);
    hipLaunchKernelGGL(rowstat_fft_kernel, dim3(NBANDS * RR / 2), dim3(256), 0, stream,
                       wc, tw, rowstats);
    hipLaunchKernelGGL(gram_kernel, dim3(NBANDS * 3), dim3(256), 0, stream,
                       wc, rowstats, A_out);
    hipLaunchKernelGGL(quantile_kernel, dim3(NBANDS), dim3(256), 0, stream, A_out, thr);
    hipLaunchKernelGGL(graph_feat_kernel, dim3(NBANDS), dim3(256), 0, stream,
                       thr, rowstats, community, W1, b1, W2, b2, A_out, F_out);
}

// Round 5
// 362.344 us; speedup vs baseline: 2.2341x; 1.2802x over previous
//
#include <hip/hip_runtime.h>
#include <hip/hip_bf16.h>
#include <math.h>
#include <float.h>

#ifndef M_PI
#define M_PI 3.14159265358979323846
#endif

// Problem constants
#define NBANDS 160      // B*NB = 32*5
#define RR 96           // rows per band
#define TT 2048         // time samples
#define NTRIL 4560      // 96*95/2
#define A_ELEMS ((size_t)NBANDS * RR * RR)
#define NBIN 16384
#define MAXCAND 512

// XOR bank swizzle for the FFT kernel
#define PHI(L) ((L) ^ (((L) >> 5) & 31))

typedef float  f32x4  __attribute__((ext_vector_type(4)));
typedef __bf16 bf16x8 __attribute__((ext_vector_type(8)));
typedef __bf16 bf16x4 __attribute__((ext_vector_type(4)));

// ---------- block reductions (256 threads) ----------
__device__ inline double blockReduceSum(double v, double* sred) {
    for (int off = 32; off > 0; off >>= 1) v += __shfl_down(v, off, 64);
    int lane = threadIdx.x & 63, wid = threadIdx.x >> 6;
    if (lane == 0) sred[wid] = v;
    __syncthreads();
    int nw = (blockDim.x + 63) >> 6;
    if (threadIdx.x == 0) {
        double r = sred[0];
        for (int i = 1; i < nw; i++) r += sred[i];
        sred[0] = r;
    }
    __syncthreads();
    double r = sred[0];
    __syncthreads();
    return r;
}

__device__ inline double blockReduceMax(double v, double* sred) {
    for (int off = 32; off > 0; off >>= 1) v = fmax(v, __shfl_down(v, off, 64));
    int lane = threadIdx.x & 63, wid = threadIdx.x >> 6;
    if (lane == 0) sred[wid] = v;
    __syncthreads();
    int nw = (blockDim.x + 63) >> 6;
    if (threadIdx.x == 0) {
        double r = sred[0];
        for (int i = 1; i < nw; i++) r = fmax(r, sred[i]);
        sred[0] = r;
    }
    __syncthreads();
    double r = sred[0];
    __syncthreads();
    return r;
}

// ---------- K0: twiddle table  tw[k] = exp(-2*pi*i*k/2048), k<1024 (fp32) ----------
__global__ void twiddle_kernel(float* tw) {
    int k = blockIdx.x * blockDim.x + threadIdx.x;
    if (k < 1024) {
        double ang = -2.0 * M_PI * (double)k / 2048.0;
        tw[2 * k]     = (float)cos(ang);
        tw[2 * k + 1] = (float)sin(ang);
    }
}

// DIT butterfly on register pair (r1, r2) with twiddle (WR, WI)
#define BFLY(r1, r2, WR, WI) do { \
    float _wr = (WR), _wi = (WI); \
    float _tr = _wr * yr[r2] - _wi * yi[r2]; \
    float _ti = _wr * yi[r2] + _wi * yr[r2]; \
    yr[r2] = yr[r1] - _tr; yi[r2] = yi[r1] - _ti; \
    yr[r1] += _tr; yi[r1] += _ti; } while (0)

// ---------- K1: per-row stats + fp32 register radix-8 FFT entropy ----------
__global__ __launch_bounds__(256) void rowstat_fft_kernel(
    const float* __restrict__ wc, const float* __restrict__ tw,
    double* __restrict__ rowstats)
{
    __shared__ float re[TT];
    __shared__ float im[TT];
    __shared__ double sred[8];
    __shared__ float bcast[4];

    int t = threadIdx.x;
    int g0 = blockIdx.x * 2;
    int g1 = g0 + 1;

    int band = g0 / RR, r0 = g0 % RR;
    int b = band / 5, nb = band % 5;
    size_t base0 = ((size_t)(b * RR + r0) * 5 + nb) * TT;
    size_t base1 = base0 + (size_t)5 * TT;

    double s0 = 0, s1 = 0, q0 = 0, q1 = 0, m0 = 0, m1 = 0;
#pragma unroll
    for (int c = 0; c < 8; c++) {
        int i = t + c * 256;
        float af = wc[base0 + i];
        float bf = wc[base1 + i];
        int P = PHI(i);
        re[P] = af; im[P] = bf;
        double a = (double)af, bb = (double)bf;
        s0 += a; s1 += bb;
        q0 += a * a; q1 += bb * bb;
        m0 = fmax(m0, fabs(a)); m1 = fmax(m1, fabs(bb));
    }
    __syncthreads();

    double SUM0 = blockReduceSum(s0, sred);
    double SUM1 = blockReduceSum(s1, sred);
    double SQ0  = blockReduceSum(q0, sred);
    double SQ1  = blockReduceSum(q1, sred);
    double MX0  = blockReduceMax(m0, sred);
    double MX1  = blockReduceMax(m1, sred);

    float yr[8], yi[8];

#pragma unroll
    for (int j = 0; j < 8; j++) {
        int p = 8 * t + j;
        int L = (int)(__brev((unsigned)p) >> 21);
        int P = PHI(L);
        yr[j] = re[P]; yi[j] = im[P];
    }

    const float RC = 0.70710678f;
    BFLY(0, 1, 1.0f, 0.0f); BFLY(2, 3, 1.0f, 0.0f);
    BFLY(4, 5, 1.0f, 0.0f); BFLY(6, 7, 1.0f, 0.0f);
    BFLY(0, 2, 1.0f, 0.0f); BFLY(1, 3, 0.0f, -1.0f);
    BFLY(4, 6, 1.0f, 0.0f); BFLY(5, 7, 0.0f, -1.0f);
    BFLY(0, 4, 1.0f, 0.0f); BFLY(1, 5, RC, -RC);
    BFLY(2, 6, 0.0f, -1.0f); BFLY(3, 7, -RC, -RC);

    __syncthreads();
#pragma unroll
    for (int j = 0; j < 8; j++) {
        int P = PHI(8 * t + j);
        re[P] = yr[j]; im[P] = yi[j];
    }
    __syncthreads();
    int oo = t & 7;
    int bb64 = 4 * ((t >> 3) & 7) + (t >> 6);
#pragma unroll
    for (int k = 0; k < 8; k++) {
        int P = PHI(64 * bb64 + 8 * k + oo);
        yr[k] = re[P]; yi[k] = im[P];
    }

    {
        int k0 = oo << 7;
        float w0r = tw[2 * k0], w0i = tw[2 * k0 + 1];
        BFLY(0, 1, w0r, w0i); BFLY(2, 3, w0r, w0i);
        BFLY(4, 5, w0r, w0i); BFLY(6, 7, w0r, w0i);
        int ka = oo << 6, kb = (oo + 8) << 6;
        float war = tw[2 * ka], wai = tw[2 * ka + 1];
        float wbr = tw[2 * kb], wbi = tw[2 * kb + 1];
        BFLY(0, 2, war, wai); BFLY(1, 3, wbr, wbi);
        BFLY(4, 6, war, wai); BFLY(5, 7, wbr, wbi);
        int kc0 = oo << 5, kc1 = (oo + 8) << 5, kc2 = (oo + 16) << 5, kc3 = (oo + 24) << 5;
        BFLY(0, 4, tw[2 * kc0], tw[2 * kc0 + 1]);
        BFLY(1, 5, tw[2 * kc1], tw[2 * kc1 + 1]);
        BFLY(2, 6, tw[2 * kc2], tw[2 * kc2 + 1]);
        BFLY(3, 7, tw[2 * kc3], tw[2 * kc3 + 1]);
    }

    __syncthreads();
#pragma unroll
    for (int k = 0; k < 8; k++) {
        int P = PHI(64 * bb64 + 8 * k + oo);
        re[P] = yr[k]; im[P] = yi[k];
    }
    __syncthreads();
    int O3 = t & 63, Wq = t >> 6;
#pragma unroll
    for (int s = 0; s < 2; s++) {
        int B3 = Wq + 4 * s;
#pragma unroll
        for (int k = 0; k < 4; k++) {
            int P = PHI(256 * B3 + 64 * k + O3);
            yr[4 * s + k] = re[P]; yi[4 * s + k] = im[P];
        }
    }

    {
        int kt = O3 << 4;
        float w0r = tw[2 * kt], w0i = tw[2 * kt + 1];
        int ka = O3 << 3, kb = (O3 + 64) << 3;
        float war = tw[2 * ka], wai = tw[2 * ka + 1];
        float wbr = tw[2 * kb], wbi = tw[2 * kb + 1];
        BFLY(0, 1, w0r, w0i); BFLY(2, 3, w0r, w0i);
        BFLY(4, 5, w0r, w0i); BFLY(6, 7, w0r, w0i);
        BFLY(0, 2, war, wai); BFLY(1, 3, wbr, wbi);
        BFLY(4, 6, war, wai); BFLY(5, 7, wbr, wbi);
    }

    __syncthreads();
#pragma unroll
    for (int s = 0; s < 2; s++) {
        int B3 = Wq + 4 * s;
#pragma unroll
        for (int k = 0; k < 4; k++) {
            int P = PHI(256 * B3 + 64 * k + O3);
            re[P] = yr[4 * s + k]; im[P] = yi[4 * s + k];
        }
    }
    __syncthreads();
#pragma unroll
    for (int k = 0; k < 8; k++) {
        int P = PHI(256 * k + t);
        yr[k] = re[P]; yi[k] = im[P];
    }

    {
        int k9 = t << 2;
        float w0r = tw[2 * k9], w0i = tw[2 * k9 + 1];
        BFLY(0, 1, w0r, w0i); BFLY(2, 3, w0r, w0i);
        BFLY(4, 5, w0r, w0i); BFLY(6, 7, w0r, w0i);
        int ka = t << 1, kb = (t + 256) << 1;
        float war = tw[2 * ka], wai = tw[2 * ka + 1];
        float wbr = tw[2 * kb], wbi = tw[2 * kb + 1];
        BFLY(0, 2, war, wai); BFLY(1, 3, wbr, wbi);
        BFLY(4, 6, war, wai); BFLY(5, 7, wbr, wbi);
        BFLY(0, 4, tw[2 * t], tw[2 * t + 1]);
        BFLY(1, 5, tw[2 * (t + 256)], tw[2 * (t + 256) + 1]);
        BFLY(2, 6, tw[2 * (t + 512)], tw[2 * (t + 512) + 1]);
        BFLY(3, 7, tw[2 * (t + 768)], tw[2 * (t + 768) + 1]);
    }

    __syncthreads();
#pragma unroll
    for (int k = 0; k < 8; k++) {
        int P = PHI(256 * k + t);
        re[P] = yr[k]; im[P] = yi[k];
    }
    __syncthreads();

    float psa[8], psb[8];
#pragma unroll
    for (int k = 0; k < 8; k++) {
        int q = (2048 - t - 256 * k) & 2047;
        int P = PHI(q);
        float prr = re[P], pii = im[P];
        float sr = yr[k] + prr, di = yi[k] - pii;
        float si = yi[k] + pii, dr = yr[k] - prr;
        psa[k] = 0.25f * (sr * sr + di * di);
        psb[k] = 0.25f * (si * si + dr * dr);
    }

    double la = 0, lb = 0;
#pragma unroll
    for (int k = 0; k < 8; k++) { la += (double)psa[k]; lb += (double)psb[k]; }
    double SAall = blockReduceSum(la, sred);
    double SBall = blockReduceSum(lb, sred);
    if (t == 0) {
        bcast[0] = psa[0]; bcast[1] = psa[4];
        bcast[2] = psb[0]; bcast[3] = psb[4];
    }
    __syncthreads();
    double Sa = 0.5 * (SAall + (double)bcast[0] - (double)bcast[1]);
    double Sb = 0.5 * (SBall + (double)bcast[2] - (double)bcast[3]);
    if (Sa == 0.0) Sa = 1.0;
    if (Sb == 0.0) Sb = 1.0;
    float invSa = (float)(1.0 / Sa), invSb = (float)(1.0 / Sb);

    double ea = 0, eb = 0;
#pragma unroll
    for (int k = 0; k < 8; k++) {
        float pa = psa[k] * invSa;
        float pb = psb[k] * invSb;
        ea += (double)(pa * logf(pa + 1e-10f));
        eb += (double)(pb * logf(pb + 1e-10f));
    }
    double EAall = blockReduceSum(ea, sred);
    double EBall = blockReduceSum(eb, sred);

    if (t == 0) {
        float pa0 = psa[0] * invSa, pa4 = psa[4] * invSa;
        float pb0 = psb[0] * invSb, pb4 = psb[4] * invSb;
        double TA = 0.5 * (EAall + (double)(pa0 * logf(pa0 + 1e-10f))
                                 - (double)(pa4 * logf(pa4 + 1e-10f)));
        double TB = 0.5 * (EBall + (double)(pb0 * logf(pb0 + 1e-10f))
                                 - (double)(pb4 * logf(pb4 + 1e-10f)));
        double mean0 = SUM0 / (double)TT;
        double mean1 = SUM1 / (double)TT;
        double nsq0 = SQ0 - (double)TT * mean0 * mean0; if (nsq0 < 0) nsq0 = 0;
        double nsq1 = SQ1 - (double)TT * mean1 * mean1; if (nsq1 < 0) nsq1 = 0;
        double* w0 = rowstats + (size_t)g0 * 6;
        double* w1 = rowstats + (size_t)g1 * 6;
        double n0 = sqrt(nsq0), n1 = sqrt(nsq1);
        w0[0] = mean0; w0[1] = (n0 == 0.0 ? 1.0 : n0); w0[2] = sqrt(nsq0 / 2047.0);
        w0[3] = SQ0;   w0[4] = MX0;                    w0[5] = -TA;
        w1[0] = mean1; w1[1] = (n1 == 0.0 ? 1.0 : n1); w1[2] = sqrt(nsq1 / 2047.0);
        w1[3] = SQ1;   w1[4] = MX1;                    w1[5] = -TB;
    }
}

// ---------- K2a: zero the Gram staging region ----------
__global__ void zero_kernel(float4* __restrict__ p, int n4) {
    int i = blockIdx.x * blockDim.x + threadIdx.x;
    if (i < n4) p[i] = make_float4(0.f, 0.f, 0.f, 0.f);
}

// ---------- K2b: MFMA Gram (hi/lo bf16 split, fp32 MFMA accum, atomic K-reduce) ----------
// grid = NBANDS * KS; block = 384 thr = 6 waves; wave w computes rows
// [16w,16w+16) x all 96 cols for its K-chunk of 256.
// LDS: hi/lo bf16 tiles 96 x 64, pitch 72 (rows 16B-aligned; bank stride 4
// -> 2-way on b128 reads = free). MFMA 16x16x32_bf16:
//   A[m=lane&15][k=quad*8+j], B[n=lane&15][k=quad*8+j] (row-major staging fits both),
//   D[row=quad*4+reg][col=lane&15]  (m89/m120-verified layouts).
#define KS 8
#define CHUNK 256
#define BKS 64
#define GPITCH 72
__global__ __launch_bounds__(384) void gram_mfma_kernel(
    const float* __restrict__ wc, float* __restrict__ G)
{
    __shared__ __attribute__((aligned(16))) __bf16 sh_hi[RR][GPITCH];
    __shared__ __attribute__((aligned(16))) __bf16 sh_lo[RR][GPITCH];

    int bid = blockIdx.x;
    int band = bid / KS, chunk = bid % KS;
    int b = band / 5, nb = band % 5;
    size_t bandbase = ((size_t)b * RR * 5 + nb) * TT + (size_t)chunk * CHUNK;

    int t = threadIdx.x;
    int wave = t >> 6, lane = t & 63;
    int m16 = lane & 15, quad = lane >> 4;
    int arow = wave * 16 + m16;

    f32x4 acc[6];
#pragma unroll
    for (int ct = 0; ct < 6; ct++) acc[ct] = (f32x4){0.f, 0.f, 0.f, 0.f};

    for (int stage = 0; stage < CHUNK / BKS; stage++) {
        int k0 = stage * BKS;
        // stage-load 96 x 64 fp32 -> hi/lo bf16 in LDS
#pragma unroll
        for (int i = 0; i < 4; i++) {
            int gid = t + i * 384;          // 0..1535
            int row = gid >> 4, c4 = gid & 15;
            float4 v = *(const float4*)(wc + bandbase + (size_t)row * (5 * TT) + k0 + c4 * 4);
            __bf16 h0 = (__bf16)v.x, h1 = (__bf16)v.y, h2 = (__bf16)v.z, h3 = (__bf16)v.w;
            __bf16 l0 = (__bf16)(v.x - (float)h0);
            __bf16 l1 = (__bf16)(v.y - (float)h1);
            __bf16 l2 = (__bf16)(v.z - (float)h2);
            __bf16 l3 = (__bf16)(v.w - (float)h3);
            *(bf16x4*)&sh_hi[row][c4 * 4] = (bf16x4){h0, h1, h2, h3};
            *(bf16x4*)&sh_lo[row][c4 * 4] = (bf16x4){l0, l1, l2, l3};
        }
        __syncthreads();
#pragma unroll
        for (int ks = 0; ks < BKS / 32; ks++) {
            int ko = ks * 32 + quad * 8;
            bf16x8 ah = *(const bf16x8*)&sh_hi[arow][ko];
            bf16x8 al = *(const bf16x8*)&sh_lo[arow][ko];
#pragma unroll
            for (int ct = 0; ct < 6; ct++) {
                int brow = ct * 16 + m16;
                bf16x8 bh = *(const bf16x8*)&sh_hi[brow][ko];
                bf16x8 bl = *(const bf16x8*)&sh_lo[brow][ko];
                acc[ct] = __builtin_amdgcn_mfma_f32_16x16x32_bf16(ah, bh, acc[ct], 0, 0, 0);
                acc[ct] = __builtin_amdgcn_mfma_f32_16x16x32_bf16(ah, bl, acc[ct], 0, 0, 0);
                acc[ct] = __builtin_amdgcn_mfma_f32_16x16x32_bf16(al, bh, acc[ct], 0, 0, 0);
            }
        }
        __syncthreads();
    }

    float* Gb = G + (size_t)band * (RR * RR);
#pragma unroll
    for (int ct = 0; ct < 6; ct++) {
#pragma unroll
        for (int r = 0; r < 4; r++) {
            int grow = wave * 16 + quad * 4 + r;
            int gcol = ct * 16 + m16;
            atomicAdd(&Gb[grow * RR + gcol], acc[ct][r]);
        }
    }
}

// ---------- K2c: normalize Gram -> correlation C (fp64 normalize, in place) ----------
__global__ __launch_bounds__(256) void normalize_kernel(
    float* __restrict__ G, const double* __restrict__ rowstats)
{
    int e = blockIdx.x * 256 + threadIdx.x;
    if (e >= (int)(NBANDS * RR * RR)) return;
    int band = e / (RR * RR);
    int rem = e % (RR * RR);
    int i = rem / RR, j = rem % RR;
    const double* rsi = rowstats + (size_t)(band * RR + i) * 6;
    const double* rsj = rowstats + (size_t)(band * RR + j) * 6;
    double c = ((double)G[e] - (double)TT * rsi[0] * rsj[0]) / (rsi[1] * rsj[1]);
    if (i == j) c = 0.0;
    G[e] = (float)c;
}

// ---------- K3: per-band 0.8-quantile of |C[tril]| via LDS histogram select ----------
__global__ __launch_bounds__(256) void quantile_kernel(
    const float* __restrict__ C, double* __restrict__ thr)
{
    __shared__ int hist[NBIN];
    __shared__ int chunk[256];
    __shared__ float cand[MAXCAND];
    __shared__ int ctrl[4];

    int band = blockIdx.x, t = threadIdx.x;
    const float* Cb = C + (size_t)band * (RR * RR);

    for (int i = t; i < NBIN; i += 256) hist[i] = 0;
    if (t == 0) ctrl[3] = 0;
    __syncthreads();

    for (int idx = t; idx < RR * RR; idx += 256) {
        int i = idx / RR, j = idx % RR;
        if (j < i) {
            float val = fabsf(Cb[idx]);
            int bin = (int)(val * (float)NBIN);
            bin = bin > (NBIN - 1) ? (NBIN - 1) : bin;
            atomicAdd(&hist[bin], 1);
        }
    }
    __syncthreads();

    int cs = 0;
    for (int i = 0; i < 64; i++) cs += hist[t * 64 + i];
    chunk[t] = cs;
    __syncthreads();

    if (t == 0) {
        int r0 = 3647, r1 = 3648;
        int cum = 0, c0 = 0;
        while (c0 < 256 && cum + chunk[c0] <= r0) { cum += chunk[c0]; c0++; }
        int bin = c0 * 64, cb = cum;
        while (cb + hist[bin] <= r0) { cb += hist[bin]; bin++; }
        int B0 = bin, cumB0 = cb;
        int bin1 = bin, cb1 = cb;
        while (cb1 + hist[bin1] <= r1) { cb1 += hist[bin1]; bin1++; }
        ctrl[0] = B0; ctrl[1] = bin1; ctrl[2] = cumB0;
    }
    __syncthreads();

    int B0 = ctrl[0], B1 = ctrl[1];
    for (int idx = t; idx < RR * RR; idx += 256) {
        int i = idx / RR, j = idx % RR;
        if (j < i) {
            float val = fabsf(Cb[idx]);
            int bin = (int)(val * (float)NBIN);
            bin = bin > (NBIN - 1) ? (NBIN - 1) : bin;
            if (bin >= B0 && bin <= B1) {
                int k = atomicAdd(&ctrl[3], 1);
                if (k < MAXCAND) cand[k] = val;
            }
        }
    }
    __syncthreads();

    if (t == 0) {
        int n = ctrl[3]; if (n > MAXCAND) n = MAXCAND;
        for (int i = 1; i < n; i++) {
            float key = cand[i]; int j = i - 1;
            while (j >= 0 && cand[j] > key) { cand[j + 1] = cand[j]; j--; }
            cand[j + 1] = key;
        }
        int r0 = 3647 - ctrl[2];
        int r1 = 3648 - ctrl[2];
        double v0 = (double)cand[r0], v1 = (double)cand[r1];
        thr[band] = v0 + 0.2 * (v1 - v0);   // pos = 0.8*(4560-1) = 3647.2
    }
}

// ---------- K4: graph props + node features + MLP; masks A in place, writes F ----------
__global__ __launch_bounds__(256) void graph_feat_kernel(
    const double* __restrict__ thrA,
    const double* __restrict__ rowstats, const int* __restrict__ community,
    const float* __restrict__ W1, const float* __restrict__ b1,
    const float* __restrict__ W2, const float* __restrict__ b2,
    float* __restrict__ A_out, float* __restrict__ F_out)
{
    __shared__ unsigned char Bm[RR][RR];
    __shared__ unsigned long long msk[RR][2];
    __shared__ int deg[RR];
    __shared__ double sred[8];
    __shared__ double feat[11];
    __shared__ double h[32];

    int band = blockIdx.x, t = threadIdx.x;
    double thr = thrA[band];
    float* Ab = A_out + (size_t)band * (RR * RR);

    for (int idx = t; idx < RR * RR; idx += 256) {
        float c = Ab[idx];
        bool keep = ((double)fabsf(c) >= thr);
        Bm[idx / RR][idx % RR] = (keep && c != 0.0f) ? 1 : 0;
        Ab[idx] = keep ? c : 0.0f;
    }
    __syncthreads();

    if (t < RR) {
        unsigned long long m0 = 0, m1 = 0; int d = 0;
        for (int j = 0; j < RR; j++) {
            if (Bm[t][j]) { d++; if (j < 64) m0 |= (1ull << j); else m1 |= (1ull << (j - 64)); }
        }
        msk[t][0] = m0; msk[t][1] = m1; deg[t] = d;
    }
    __syncthreads();

    double triord = 0, ein = 0, expin = 0;
    for (int idx = t; idx < RR * RR; idx += 256) {
        int i = idx / RR, j = idx % RR;
        if (Bm[i][j])
            triord += (double)(__popcll(msk[i][0] & msk[j][0]) +
                               __popcll(msk[i][1] & msk[j][1]));
        if (i != j && community[i] == community[j]) {
            ein += (double)Bm[i][j];
            expin += (double)deg[i] * (double)deg[j];
        }
    }
    double TRI   = blockReduceSum(triord, sred);
    double EIN   = blockReduceSum(ein, sred);
    double EXPIN = blockReduceSum(expin, sred);
    double dv = (t < RR) ? (double)deg[t] : 0.0;
    double DEGS = blockReduceSum(dv, sred);
    double POSS2 = blockReduceSum((t < RR) ? dv * (dv - 1.0) : 0.0, sred);

    const double* rs = rowstats + (size_t)band * RR * 6;
    double N0 = blockReduceSum((t < RR) ? rs[t * 6 + 0] : 0.0, sred);
    double N1 = blockReduceSum((t < RR) ? rs[t * 6 + 2] : 0.0, sred);
    double N2 = blockReduceSum((t < RR) ? rs[t * 6 + 3] : 0.0, sred);
    double N3 = blockReduceSum((t < RR) ? rs[t * 6 + 4] : 0.0, sred);
    double N4 = blockReduceSum((t < RR) ? rs[t * 6 + 5] : 0.0, sred);

    if (t == 0) {
        double ne = 0.5 * DEGS;
        feat[0] = N0 / (double)RR;
        feat[1] = N1 / (double)RR;
        feat[2] = N2 / (double)RR;
        feat[3] = N3 / (double)RR;
        feat[4] = N4 / (double)RR;
        feat[5] = ne;
        feat[6] = ne / (double)NTRIL;
        feat[7] = DEGS / (double)RR;
        double tri = TRI / 6.0, poss = POSS2 * 0.5;
        feat[8] = (poss > 0.0) ? tri / poss : 0.0;
        feat[9] = ((double)RR + DEGS) / ((double)RR * (double)(RR - 1));
        double m2 = DEGS;
        feat[10] = (m2 > 0.0) ? (EIN - EXPIN / m2) / m2 : 0.0;
    }
    __syncthreads();

    if (t < 32) {
        double a = (double)b1[t];
        for (int k = 0; k < 11; k++) a += (double)W1[t * 11 + k] * feat[k];
        h[t] = (a > 0.0) ? a : 0.0;
    }
    __syncthreads();
    if (t < 64) {
        double a = (double)b2[t];
        for (int j = 0; j < 32; j++) a += (double)W2[t * 32 + j] * h[j];
        F_out[(size_t)band * 64 + t] = (float)a;
    }
}

extern "C" void kernel_launch(void* const* d_in, const int* in_sizes, int n_in,
                              void* d_out, int out_size, void* d_ws, size_t ws_size,
                              hipStream_t stream) {
    const float* wc        = (const float*)d_in[0];
    // d_in[1] frequency_bands: unused by the reference math
    const int*   community = (const int*)d_in[2];
    const float* W1        = (const float*)d_in[3];
    const float* b1        = (const float*)d_in[4];
    const float* W2        = (const float*)d_in[5];
    const float* b2        = (const float*)d_in[6];

    float* A_out = (float*)d_out;          // Gram staged here, normalized, masked in place
    float* F_out = A_out + A_ELEMS;

    // workspace: tw 8192 B | rowstats 15360*6*8 = 737280 B | thr 160*8 B  => ~746 KB
    char* ws = (char*)d_ws;
    float*  tw       = (float*)ws;
    double* rowstats = (double*)(ws + 8192);
    double* thr      = (double*)(ws + 8192 + 737280);

    int n4 = (int)(A_ELEMS / 4);           // 368640
    hipLaunchKernelGGL(twiddle_kernel, dim3(4), dim3(256), 0, stream, tw);
    hipLaunchKernelGGL(rowstat_fft_kernel, dim3(NBANDS * RR / 2), dim3(256), 0, stream,
                       wc, tw, rowstats);
    hipLaunchKernelGGL(zero_kernel, dim3((n4 + 255) / 256), dim3(256), 0, stream,
                       (float4*)A_out, n4);
    hipLaunchKernelGGL(gram_mfma_kernel, dim3(NBANDS * KS), dim3(384), 0, stream,
                       wc, A_out);
    hipLaunchKernelGGL(normalize_kernel,
                       dim3((int)((NBANDS * RR * RR + 255) / 256)), dim3(256), 0, stream,
                       A_out, rowstats);
    hipLaunchKernelGGL(quantile_kernel, dim3(NBANDS), dim3(256), 0, stream, A_out, thr);
    hipLaunchKernelGGL(graph_feat_kernel, dim3(NBANDS), dim3(256), 0, stream,
                       thr, rowstats, community, W1, b1, W2, b2, A_out, F_out);
}